// Round 8
// baseline (249.170 us; speedup 1.0000x reference)
//
#include <hip/hip_runtime.h>
#include <math.h>

#define NN 50000
#define NE 600000
#define D 128
#define NH 3
#define CAP 64                              // max degree bucket (lambda=12, P(>=64)~1e-30)
#define SCAT_BLOCKS ((NE + 127) / 128)      // 4688 edge-scatter blocks (128 thr)
#define MF_BLOCKS ((NN + 31) / 32)          // 1563 mfma blocks (32-row tiles)
#define SC_BLOCKS ((NN + 255) / 256)        // 196 score-role blocks (256 rows each)
#define FG_BLOCKS ((NN + 63) / 64)          // 782 final-gemm blocks
#define LOG2E 1.44269504088896340736f

typedef short bf16x8 __attribute__((ext_vector_type(8)));
typedef _Float16 f16x8 __attribute__((ext_vector_type(8)));
typedef float f32x4 __attribute__((ext_vector_type(4)));

__device__ __forceinline__ unsigned short f2b(float f) {
  unsigned int u = __float_as_uint(f);
  u += 0x7FFF + ((u >> 16) & 1);            // round-to-nearest-even
  return (unsigned short)(u >> 16);
}
__device__ __forceinline__ float blo(unsigned int u) {
  return __uint_as_float(u << 16);
}
__device__ __forceinline__ float bhi(unsigned int u) {
  return __uint_as_float(u & 0xffff0000u);
}
__device__ __forceinline__ unsigned short f2h(float f) {
  _Float16 t = (_Float16)f;
  return *(unsigned short*)&t;
}

// ---------------------------------------------------------------------------
// prep0: tiny fully-parallel front node (82 blocks, ~4 us). No serial dots.
//  bx < 49 : zero counts (12500 int4)
//  bx < 57 : W_lin fp32 -> Bpack bf16 (2048 units)
//  bx < 81 : W_heads -> Wpack3 fp16 (6144 units)
//  bx ==81 : bcomb2 = (sum_h bias_h)/3
// ---------------------------------------------------------------------------
__global__ __launch_bounds__(256) void prep0(const float* __restrict__ W_lin,
                                             const float* __restrict__ W_heads,
                                             const float* __restrict__ bias_heads,
                                             uint4* __restrict__ Bpack,
                                             uint4* __restrict__ Wpack3,
                                             float* __restrict__ bcomb2,
                                             int* __restrict__ counts) {
  const int bx = blockIdx.x;
  const int tid = threadIdx.x;
  if (bx < 49) {
    int i = bx * 256 + tid;
    if (i < NN / 4) ((int4*)counts)[i] = make_int4(0, 0, 0, 0);
  } else if (bx < 57) {
    int r = (bx - 49) * 256 + tid;       // 0..2047
    int nt = r >> 8, s = (r >> 6) & 3, q = (r >> 4) & 3, n0 = r & 15;
    int kbase = s * 32 + q * 8;
    int n = nt * 16 + n0;
    unsigned int w[4];
    #pragma unroll
    for (int p = 0; p < 4; ++p) {
      unsigned short lo = f2b(W_lin[(kbase + 2 * p) * D + n]);
      unsigned short hi = f2b(W_lin[(kbase + 2 * p + 1) * D + n]);
      w[p] = (unsigned int)lo | ((unsigned int)hi << 16);
    }
    Bpack[r] = make_uint4(w[0], w[1], w[2], w[3]);
  } else if (bx < 81) {
    int u = (bx - 57) * 256 + tid;       // 0..6143
    int h = u >> 11, r = u & 2047;
    int nt = r >> 8, s = (r >> 6) & 3, q = (r >> 4) & 3, n0 = r & 15;
    int kbase = s * 32 + q * 8;
    int n = nt * 16 + n0;
    const float* W = W_heads + (size_t)h * D * D;
    unsigned int w[4];
    #pragma unroll
    for (int p = 0; p < 4; ++p) {
      unsigned short lo = f2h(W[(kbase + 2 * p) * D + n]);
      unsigned short hi = f2h(W[(kbase + 2 * p + 1) * D + n]);
      w[p] = (unsigned int)lo | ((unsigned int)hi << 16);
    }
    Wpack3[h * 2048 + r] = make_uint4(w[0], w[1], w[2], w[3]);
  } else {
    if (tid < D)
      bcomb2[tid] = (bias_heads[tid] + bias_heads[D + tid] + bias_heads[2 * D + tid]) * (1.f / 3.f);
  }
}

// ---------------------------------------------------------------------------
// scatmm: the whole front-end in ONE dispatch. Scatter blocks first (latency
// pole starts at t=0, VALU 0.6% idle); mfma and score blocks fill the idle
// pipes. No intra-kernel dependencies: scatter needs counts=0 (prep0), mfma
// needs Bpack (prep0), score role reads raw x/W/att only.
//  bx < 4688           : edge scatter (128 thr, 1 edge/thread)
//  bx < 4688+1563      : x_tilde 32-row MFMA tile -> xb (no score tile)
//  bx < 4688+1563+196  : scores from raw x: s = x.(LOG2E*W_lin@wha) + sb
// ---------------------------------------------------------------------------
__global__ __launch_bounds__(128) void scatmm(const float* __restrict__ x,
                                              const uint4* __restrict__ Bpack,
                                              const float* __restrict__ b_lin,
                                              const float* __restrict__ W_lin,
                                              const float* __restrict__ W_heads,
                                              const float* __restrict__ att_src,
                                              const float* __restrict__ att_dst,
                                              const int* __restrict__ ei,
                                              const int* __restrict__ eid,
                                              const float* __restrict__ ddi,
                                              const float* __restrict__ emb,
                                              unsigned short* __restrict__ xb,
                                              float* __restrict__ s_src4,
                                              float* __restrict__ s_dst4,
                                              int* __restrict__ counts,
                                              unsigned int* __restrict__ slots8) {
  const int bx = blockIdx.x;
  const int tid = threadIdx.x;              // 0..127
  __shared__ __align__(16) unsigned char smem[8704];
  if (bx < SCAT_BLOCKS) {
    // ----- scatter role -----
    int e = bx * 128 + tid;
    if (e < NE) {
      int src = ei[e], dst = ei[NE + e];
      int idx = atomicAdd(&counts[dst], 1);
      idx = idx < CAP ? idx : CAP - 1;   // safety clamp (statistically unreachable)
      float ew = emb[eid[e]] - ddi[e];
      slots8[dst * CAP + idx] = (unsigned int)src | ((unsigned int)f2b(ew) << 16);
    }
  } else if (bx < SCAT_BLOCKS + MF_BLOCKS) {
    // ----- mfma role: x_tilde = x@W_lin + b_lin -> bf16 [32 rows] -----
    unsigned short (*As)[136] = (unsigned short(*)[136])smem;
    const int row0 = (bx - SCAT_BLOCKS) * 32;
    #pragma unroll
    for (int it = 0; it < 8; ++it) {
      int idx = tid + it * 128;             // 0..1023 = 32 rows x 32 k4
      int m = idx >> 5, k4 = idx & 31;
      int row = row0 + m;
      float4 v = make_float4(0.f, 0.f, 0.f, 0.f);
      if (row < NN) v = ((const float4*)(x + (size_t)row * D))[k4];
      uint2 pk;
      pk.x = (unsigned int)f2b(v.x) | ((unsigned int)f2b(v.y) << 16);
      pk.y = (unsigned int)f2b(v.z) | ((unsigned int)f2b(v.w) << 16);
      *((uint2*)&As[m][k4 * 4]) = pk;
    }
    __syncthreads();
    const int wv = tid >> 6;                // 0..1
    const int lane = tid & 63;
    const int n0 = lane & 15, q = lane >> 4;
    const int boff = q * 16 + n0;
    const bf16x8* Bp = (const bf16x8*)Bpack;
    bf16x8 a4[4];
    #pragma unroll
    for (int s = 0; s < 4; ++s)
      a4[s] = *(const bf16x8*)&As[wv * 16 + n0][s * 32 + q * 8];
    f32x4 acc[8];
    #pragma unroll
    for (int nt = 0; nt < 8; ++nt) acc[nt] = (f32x4){0.f, 0.f, 0.f, 0.f};
    #pragma unroll
    for (int s = 0; s < 4; ++s) {
      #pragma unroll
      for (int nt = 0; nt < 8; ++nt) {
        bf16x8 b = Bp[(nt * 4 + s) * 64 + boff];
        acc[nt] = __builtin_amdgcn_mfma_f32_16x16x32_bf16(a4[s], b, acc[nt], 0, 0, 0);
      }
    }
    __syncthreads();   // both waves hoisted a4; As dead -> reuse as out-tile
    #pragma unroll
    for (int nt = 0; nt < 8; ++nt) {
      int col = nt * 16 + n0;
      float bv = b_lin[col];
      #pragma unroll
      for (int r = 0; r < 4; ++r)
        As[wv * 16 + q * 4 + r][col] = f2b(acc[nt][r] + bv);
    }
    __syncthreads();
    #pragma unroll
    for (int i = 0; i < 4; ++i) {
      int idx = tid + i * 128;              // 0..511
      int row = idx >> 4, c16 = idx & 15;
      int grow = row0 + row;
      if (grow < NN)
        *((uint4*)&xb[(size_t)grow * D + c16 * 8]) = *((const uint4*)&As[row][c16 * 8]);
    }
  } else {
    // ----- score role: 256 rows/block, fp32, pre-scaled by LOG2E -----
    float* wha = (float*)smem;              // [128][8] (6 used)
    float* scs = wha + 128 * 8;             // won't fit: use second region below
    // smem is 8704B = 2176 floats; need 128*8*2 = 2048 floats -> fits.
    scs = wha + 1024;                       // [128][8]
    __shared__ float sbv[8];
    const int row0 = (bx - (SCAT_BLOCKS + MF_BLOCKS)) * 256;
    const int t = tid;                      // 0..127
    // wha[c][2h+d] = dot(W_heads[h][c][:], att_{src/dst}[h][:])
    #pragma unroll
    for (int h = 0; h < NH; ++h) {
      const float* Wr = W_heads + (size_t)h * D * D + t * D;
      const float* as = att_src + h * D;
      const float* ad = att_dst + h * D;
      float aS = 0.f, aD = 0.f;
      for (int n = 0; n < D; ++n) { float w = Wr[n]; aS += w * as[n]; aD += w * ad[n]; }
      wha[t * 8 + 2 * h] = aS;
      wha[t * 8 + 2 * h + 1] = aD;
    }
    __syncthreads();
    // scs[k][j] = LOG2E * dot(W_lin[k][:], wha[:][j])
    {
      const float* wl = W_lin + t * D;
      float a[6] = {0.f, 0.f, 0.f, 0.f, 0.f, 0.f};
      for (int m = 0; m < D; ++m) {
        float w = wl[m];
        #pragma unroll
        for (int j = 0; j < 6; ++j) a[j] += w * wha[m * 8 + j];
      }
      #pragma unroll
      for (int j = 0; j < 6; ++j) scs[t * 8 + j] = a[j] * LOG2E;
    }
    if (t < 6) {
      float a = 0.f;
      for (int k = 0; k < D; ++k) a += b_lin[k] * wha[k * 8 + t];
      sbv[t] = a * LOG2E;
    }
    __syncthreads();
    // rows: each thread 2 rows; scs reads are wave-uniform broadcasts
    for (int rr = 0; rr < 2; ++rr) {
      int row = row0 + rr * 128 + t;
      if (row < NN) {
        const float4* xr = (const float4*)(x + (size_t)row * D);
        float a[6] = {0.f, 0.f, 0.f, 0.f, 0.f, 0.f};
        for (int k4 = 0; k4 < 32; ++k4) {
          float4 v = xr[k4];
          const float* s0 = &scs[(k4 * 4) * 8];
          #pragma unroll
          for (int j = 0; j < 6; ++j)
            a[j] += v.x * s0[j] + v.y * s0[8 + j] + v.z * s0[16 + j] + v.w * s0[24 + j];
        }
        #pragma unroll
        for (int h = 0; h < NH; ++h) {
          s_src4[row * 4 + h] = a[2 * h] + sbv[2 * h];
          s_dst4[row * 4 + h] = a[2 * h + 1] + sbv[2 * h + 1];
        }
      }
    }
  }
}

// ---------------------------------------------------------------------------
// gather12: unchanged (control). 1 wave/dst, exp2, fp16 acc [NN][384].
// ---------------------------------------------------------------------------
__global__ __launch_bounds__(64) void gather12(const int* __restrict__ counts,
                                               const unsigned int* __restrict__ slots8,
                                               const float4* __restrict__ s_src4,
                                               const float4* __restrict__ s_dst4,
                                               const unsigned short* __restrict__ xb,
                                               unsigned short* __restrict__ accb) {
  const int dst = blockIdx.x;
  const int lane = threadIdx.x;          // 0..63
  const int hf = lane >> 5;
  const int c = (lane & 31) * 4;         // channel base (4 channels per lane)
  int cnt = counts[dst];
  cnt = cnt < CAP ? cnt : CAP;
  const int beg = dst * CAP;
  const int end = beg + cnt;
  float4 sd = s_dst4[dst];
  float a0[4] = {0.f, 0.f, 0.f, 0.f};
  float a1[4] = {0.f, 0.f, 0.f, 0.f};
  float a2[4] = {0.f, 0.f, 0.f, 0.f};
  float d0 = 0.f, d1 = 0.f, d2 = 0.f;
  int s = beg + hf;
  for (; s + 2 < end; s += 4) {
    unsigned int seA = slots8[s];
    unsigned int seB = slots8[s + 2];
    int srcA = seA & 0xffffu, srcB = seB & 0xffffu;
    float ewA = bhi(seA), ewB = bhi(seB);
    float4 ssA = s_src4[srcA];
    float4 ssB = s_src4[srcB];
    uint2 ua = *(const uint2*)&xb[(size_t)srcA * D + c];
    uint2 ub = *(const uint2*)&xb[(size_t)srcB * D + c];
    float vA0 = ssA.x + sd.x, vA1 = ssA.y + sd.y, vA2 = ssA.z + sd.z;
    float vB0 = ssB.x + sd.x, vB1 = ssB.y + sd.y, vB2 = ssB.z + sd.z;
    vA0 = vA0 > 0.f ? vA0 : 0.2f * vA0;
    vA1 = vA1 > 0.f ? vA1 : 0.2f * vA1;
    vA2 = vA2 > 0.f ? vA2 : 0.2f * vA2;
    vB0 = vB0 > 0.f ? vB0 : 0.2f * vB0;
    vB1 = vB1 > 0.f ? vB1 : 0.2f * vB1;
    vB2 = vB2 > 0.f ? vB2 : 0.2f * vB2;
    // scores pre-scaled by log2(e): exp(orig) == exp2(v); alpha identical
    float pA0 = exp2f(vA0), pA1 = exp2f(vA1), pA2 = exp2f(vA2);
    float pB0 = exp2f(vB0), pB1 = exp2f(vB1), pB2 = exp2f(vB2);
    float wa0 = pA0 * ewA, wa1 = pA1 * ewA, wa2 = pA2 * ewA;
    float wb0 = pB0 * ewB, wb1 = pB1 * ewB, wb2 = pB2 * ewB;
    float xA[4] = {blo(ua.x), bhi(ua.x), blo(ua.y), bhi(ua.y)};
    float xB[4] = {blo(ub.x), bhi(ub.x), blo(ub.y), bhi(ub.y)};
    #pragma unroll
    for (int j = 0; j < 4; ++j) {
      a0[j] += wa0 * xA[j] + wb0 * xB[j];
      a1[j] += wa1 * xA[j] + wb1 * xB[j];
      a2[j] += wa2 * xA[j] + wb2 * xB[j];
    }
    d0 += pA0 + pB0;
    d1 += pA1 + pB1;
    d2 += pA2 + pB2;
  }
  if (s < end) {
    unsigned int seA = slots8[s];
    int srcA = seA & 0xffffu;
    float ewA = bhi(seA);
    float4 ssA = s_src4[srcA];
    uint2 ua = *(const uint2*)&xb[(size_t)srcA * D + c];
    float vA0 = ssA.x + sd.x, vA1 = ssA.y + sd.y, vA2 = ssA.z + sd.z;
    vA0 = vA0 > 0.f ? vA0 : 0.2f * vA0;
    vA1 = vA1 > 0.f ? vA1 : 0.2f * vA1;
    vA2 = vA2 > 0.f ? vA2 : 0.2f * vA2;
    float pA0 = exp2f(vA0), pA1 = exp2f(vA1), pA2 = exp2f(vA2);
    float w0 = pA0 * ewA, w1 = pA1 * ewA, w2 = pA2 * ewA;
    float xA[4] = {blo(ua.x), bhi(ua.x), blo(ua.y), bhi(ua.y)};
    #pragma unroll
    for (int j = 0; j < 4; ++j) {
      a0[j] += w0 * xA[j];
      a1[j] += w1 * xA[j];
      a2[j] += w2 * xA[j];
    }
    d0 += pA0; d1 += pA1; d2 += pA2;
  }
  #pragma unroll
  for (int j = 0; j < 4; ++j) {
    a0[j] += __shfl_xor(a0[j], 32, 64);
    a1[j] += __shfl_xor(a1[j], 32, 64);
    a2[j] += __shfl_xor(a2[j], 32, 64);
  }
  d0 += __shfl_xor(d0, 32, 64);
  d1 += __shfl_xor(d1, 32, 64);
  d2 += __shfl_xor(d2, 32, 64);
  if (hf == 0) {
    float r0 = 1.f / (3.f * fmaxf(d0, 1e-16f));   // fold 1/NH here
    float r1 = 1.f / (3.f * fmaxf(d1, 1e-16f));
    float r2 = 1.f / (3.f * fmaxf(d2, 1e-16f));
    unsigned short* base = accb + (size_t)dst * (NH * D);
    uint2 o;
    o.x = (unsigned int)f2h(a0[0] * r0) | ((unsigned int)f2h(a0[1] * r0) << 16);
    o.y = (unsigned int)f2h(a0[2] * r0) | ((unsigned int)f2h(a0[3] * r0) << 16);
    *(uint2*)&base[c] = o;
    o.x = (unsigned int)f2h(a1[0] * r1) | ((unsigned int)f2h(a1[1] * r1) << 16);
    o.y = (unsigned int)f2h(a1[2] * r1) | ((unsigned int)f2h(a1[3] * r1) << 16);
    *(uint2*)&base[D + c] = o;
    o.x = (unsigned int)f2h(a2[0] * r2) | ((unsigned int)f2h(a2[1] * r2) << 16);
    o.y = (unsigned int)f2h(a2[2] * r2) | ((unsigned int)f2h(a2[3] * r2) << 16);
    *(uint2*)&base[2 * D + c] = o;
  }
}

// ---------------------------------------------------------------------------
// final_gemm16: unchanged r6 version (control). Single-pass f16 MFMA.
// ---------------------------------------------------------------------------
__global__ __launch_bounds__(256) void final_gemm16(const unsigned short* __restrict__ accb,
                                                    const uint4* __restrict__ Wpack3,
                                                    const float* __restrict__ bcomb2,
                                                    float* __restrict__ out) {
  const int row0 = blockIdx.x * 64;
  const int tid = threadIdx.x;
  __shared__ __align__(16) _Float16 Af[64][136];
  const int wv = tid >> 6;
  const int lane = tid & 63;
  const int n0 = lane & 15, q = lane >> 4;
  const int boff = q * 16 + n0;

  f32x4 o[8];
  #pragma unroll
  for (int nt = 0; nt < 8; ++nt) o[nt] = (f32x4){0.f, 0.f, 0.f, 0.f};

  for (int ck = 0; ck < NH; ++ck) {
    if (ck) __syncthreads();              // prior frag reads done before restage
    #pragma unroll
    for (int it = 0; it < 4; ++it) {
      int idx = tid + it * 256;           // 0..1023
      int m = idx >> 4, k8 = idx & 15;
      int row = row0 + m;
      uint4 u = make_uint4(0, 0, 0, 0);
      if (row < NN)
        u = *(const uint4*)&accb[(size_t)row * (NH * D) + ck * D + k8 * 8];
      *((uint4*)&Af[m][k8 * 8]) = u;      // direct copy: accb is already fp16
    }
    __syncthreads();
    f16x8 af[4];
    #pragma unroll
    for (int s = 0; s < 4; ++s)
      af[s] = *(const f16x8*)&Af[wv * 16 + n0][s * 32 + q * 8];
    const f16x8* Bp = (const f16x8*)(Wpack3 + ck * 2048);
    #pragma unroll
    for (int s = 0; s < 4; ++s) {
      #pragma unroll
      for (int nt = 0; nt < 8; ++nt) {
        f16x8 b = Bp[(nt * 4 + s) * 64 + boff];
        o[nt] = __builtin_amdgcn_mfma_f32_16x16x32_f16(af[s], b, o[nt], 0, 0, 0);
      }
    }
  }
  // epilogue: 16-lane groups write 64B-contiguous fp32 segments
  #pragma unroll
  for (int nt = 0; nt < 8; ++nt) {
    int col = nt * 16 + n0;
    float bv = bcomb2[col];
    #pragma unroll
    for (int r = 0; r < 4; ++r) {
      int row = row0 + wv * 16 + q * 4 + r;
      if (row < NN) out[(size_t)row * D + col] = o[nt][r] + bv;
    }
  }
}

// ---------------------------------------------------------------------------
extern "C" void kernel_launch(void* const* d_in, const int* in_sizes, int n_in,
                              void* d_out, int out_size, void* d_ws, size_t ws_size,
                              hipStream_t stream) {
  const float* x          = (const float*)d_in[0];
  const int*   ei         = (const int*)d_in[1];
  const int*   eid        = (const int*)d_in[2];
  const float* ddi        = (const float*)d_in[3];
  const float* W_lin      = (const float*)d_in[4];
  const float* b_lin      = (const float*)d_in[5];
  const float* emb        = (const float*)d_in[6];
  const float* W_heads    = (const float*)d_in[7];
  const float* att_src    = (const float*)d_in[8];
  const float* att_dst    = (const float*)d_in[9];
  const float* bias_heads = (const float*)d_in[10];
  float* out = (float*)d_out;

  // workspace layout (16B-aligned chunks first); total ~66 MB
  uint4*  Bpack  = (uint4*)d_ws;                               // 2304 (2048 used)
  uint4*  Wpack3 = Bpack + 2304;                               // 3*2048 (W_heads fp16)
  unsigned short* xb = (unsigned short*)(Wpack3 + NH * 2048);  // NN*D bf16 (12.8MB)
  unsigned int* slots8 = (unsigned int*)(xb + (size_t)NN * D); // NN*CAP (12.8MB)
  unsigned short* accb = (unsigned short*)(slots8 + (size_t)NN * CAP); // NN*384 fp16 (38.4MB)
  float*  bcomb2 = (float*)(accb + (size_t)NN * NH * D);       // 128
  float*  s_src4 = bcomb2 + 128;                               // NN*4 (stride-4)
  float*  s_dst4 = s_src4 + (size_t)NN * 4;                    // NN*4
  int*    counts = (int*)(s_dst4 + (size_t)NN * 4);            // NN

  // 1. tiny parallel prep: zero counts + W repacks + bcomb2 (no memset node)
  prep0<<<82, 256, 0, stream>>>(W_lin, W_heads, bias_heads, Bpack, Wpack3,
                                bcomb2, counts);
  // 2. fused front-end: scatter (t=0, latency pole) || mfma x_tilde || scores
  scatmm<<<SCAT_BLOCKS + MF_BLOCKS + SC_BLOCKS, 128, 0, stream>>>(
      x, Bpack, b_lin, W_lin, W_heads, att_src, att_dst, ei, eid, ddi, emb,
      xb, s_src4, s_dst4, counts, slots8);
  // 3. per-dst gather (control)
  gather12<<<NN, 64, 0, stream>>>(counts, slots8, (const float4*)s_src4,
                                  (const float4*)s_dst4, xb, accb);
  // 4. dense epilogue (control)
  final_gemm16<<<FG_BLOCKS, 256, 0, stream>>>(accb, Wpack3, bcomb2, out);
}

// Round 9
// 212.781 us; speedup vs baseline: 1.1710x; 1.1710x over previous
//
#include <hip/hip_runtime.h>
#include <math.h>

#define NN 50000
#define NE 600000
#define D 128
#define NH 3
#define CAP 64                              // max degree bucket (lambda=12, P(>=64)~1e-30)
#define EDGE_BLOCKS ((NE + 255) / 256)      // 2344
#define MFMA_BLOCKS ((NN + 63) / 64)        // 782
#define LOG2E 1.44269504088896340736f

typedef short bf16x8 __attribute__((ext_vector_type(8)));
typedef _Float16 f16x8 __attribute__((ext_vector_type(8)));
typedef float f32x4 __attribute__((ext_vector_type(4)));

extern "C" __device__ float __ocml_native_exp2_f32(float);   // single v_exp_f32

__device__ __forceinline__ unsigned short f2b(float f) {
  unsigned int u = __float_as_uint(f);
  u += 0x7FFF + ((u >> 16) & 1);            // round-to-nearest-even
  return (unsigned short)(u >> 16);
}
__device__ __forceinline__ float blo(unsigned int u) {
  return __uint_as_float(u << 16);
}
__device__ __forceinline__ float bhi(unsigned int u) {
  return __uint_as_float(u & 0xffff0000u);
}
__device__ __forceinline__ unsigned short f2h(float f) {
  _Float16 t = (_Float16)f;
  return *(unsigned short*)&t;
}

// ---------------------------------------------------------------------------
// pack_scatter2: unchanged r6 (control). Scatter + tiny prep roles only —
// the ONLY fusion pattern that works (r1/r5/r8: scatter+MFMA roles condemned).
// ---------------------------------------------------------------------------
__global__ __launch_bounds__(256) void pack_scatter2(const float* __restrict__ W_lin,
                                                     const float* __restrict__ W_heads,
                                                     const float* __restrict__ att_src,
                                                     const float* __restrict__ att_dst,
                                                     const float* __restrict__ b_lin,
                                                     const float* __restrict__ bias_heads,
                                                     const int* __restrict__ ei,
                                                     const int* __restrict__ eid,
                                                     const float* __restrict__ ddi,
                                                     const float* __restrict__ emb,
                                                     uint4* __restrict__ Bpack,
                                                     uint4* __restrict__ Wpack3,
                                                     float* __restrict__ sbuf,
                                                     float* __restrict__ bcomb2,
                                                     int* __restrict__ counts,
                                                     unsigned int* __restrict__ slots8) {
  const int bx = blockIdx.x;
  const int tid = threadIdx.x;
  if (bx < EDGE_BLOCKS) {
    int e = bx * 256 + tid;
    if (e < NE) {
      int src = ei[e], dst = ei[NE + e];
      int idx = atomicAdd(&counts[dst], 1);
      idx = idx < CAP ? idx : CAP - 1;   // safety clamp (statistically unreachable)
      float ew = emb[eid[e]] - ddi[e];
      slots8[dst * CAP + idx] = (unsigned int)src | ((unsigned int)f2b(ew) << 16);
    }
    return;
  }
  const int pb = bx - EDGE_BLOCKS;
  if (pb < 8) {
    int r = pb * 256 + tid;              // 0..2047
    int nt = r >> 8, s = (r >> 6) & 3, q = (r >> 4) & 3, n0 = r & 15;
    int kbase = s * 32 + q * 8;
    int n = nt * 16 + n0;
    unsigned int w[4];
    #pragma unroll
    for (int p = 0; p < 4; ++p) {
      unsigned short lo = f2b(W_lin[(kbase + 2 * p) * D + n]);
      unsigned short hi = f2b(W_lin[(kbase + 2 * p + 1) * D + n]);
      w[p] = (unsigned int)lo | ((unsigned int)hi << 16);
    }
    Bpack[r] = make_uint4(w[0], w[1], w[2], w[3]);
  } else if (pb < 32) {
    int u = (pb - 8) * 256 + tid;        // 0..6143
    int h = u >> 11, r = u & 2047;
    int nt = r >> 8, s = (r >> 6) & 3, q = (r >> 4) & 3, n0 = r & 15;
    int kbase = s * 32 + q * 8;
    int n = nt * 16 + n0;
    const float* W = W_heads + (size_t)h * D * D;
    unsigned int w[4];
    #pragma unroll
    for (int p = 0; p < 4; ++p) {
      unsigned short lo = f2h(W[(kbase + 2 * p) * D + n]);
      unsigned short hi = f2h(W[(kbase + 2 * p + 1) * D + n]);
      w[p] = (unsigned int)lo | ((unsigned int)hi << 16);
    }
    Wpack3[h * 2048 + r] = make_uint4(w[0], w[1], w[2], w[3]);
  } else if (pb < 35) {
    const int h = pb - 32;
    __shared__ float wha_s[128], wha_d[128], scs[128], scd[128];
    {
      int m = tid & 127;
      const float* W = W_heads + (size_t)h * D * D + m * D;
      const float* a = (tid < 128) ? (att_src + h * D) : (att_dst + h * D);
      float acc = 0.f;
      for (int n = 0; n < D; ++n) acc += W[n] * a[n];
      if (tid < 128) wha_s[m] = acc; else wha_d[m] = acc;
    }
    __syncthreads();
    {
      int k = tid & 127;
      const float* wl = W_lin + k * D;
      const float* wha = (tid < 128) ? wha_s : wha_d;
      float acc = 0.f;
      for (int m = 0; m < D; ++m) acc += wl[m] * wha[m];
      if (tid < 128) scs[k] = acc * LOG2E; else scd[k] = acc * LOG2E;
    }
    __syncthreads();
    if (tid < 2) {
      const float* wha = tid ? wha_d : wha_s;
      float a = 0.f;
      for (int k = 0; k < D; ++k) a += b_lin[k] * wha[k];
      sbuf[h * 2 + tid] = a * LOG2E;     // sbuf = [s0,d0,s1,d1,s2,d2] (scaled)
    }
    {
      int s = (tid >> 6) & 3, q = (tid >> 4) & 3, n0 = tid & 15;
      int kbase = s * 32 + q * 8;
      bool mine = (n0 < 6) && ((n0 >> 1) == h);
      bool zero = (h == 0) && (n0 >= 6);
      if (mine || zero) {
        float vals[8];
        #pragma unroll
        for (int j = 0; j < 8; ++j)
          vals[j] = zero ? 0.f : ((n0 & 1) ? scd[kbase + j] : scs[kbase + j]);
        unsigned int w[4];
        #pragma unroll
        for (int p = 0; p < 4; ++p)
          w[p] = (unsigned int)f2b(vals[2 * p]) | ((unsigned int)f2b(vals[2 * p + 1]) << 16);
        Bpack[2048 + tid] = make_uint4(w[0], w[1], w[2], w[3]);
      }
    }
  } else {
    if (tid < D)
      bcomb2[tid] = (bias_heads[tid] + bias_heads[D + tid] + bias_heads[2 * D + tid]) * (1.f / 3.f);
  }
}

// ---------------------------------------------------------------------------
// mfma_x: unchanged r6 (control).
// ---------------------------------------------------------------------------
__global__ __launch_bounds__(256) void mfma_x(const float* __restrict__ x,
                                              const uint4* __restrict__ Bpack,
                                              const float* __restrict__ b_lin,
                                              const float* __restrict__ sbuf,
                                              unsigned short* __restrict__ xb,
                                              float* __restrict__ s_src4,
                                              float* __restrict__ s_dst4) {
  const int row0 = blockIdx.x * 64;
  const int tid = threadIdx.x;
  __shared__ __align__(16) unsigned short As[64][136];
  #pragma unroll
  for (int it = 0; it < 8; ++it) {
    int idx = tid + it * 256;
    int m = idx >> 5, k4 = idx & 31;
    int row = row0 + m;
    float4 v = make_float4(0.f, 0.f, 0.f, 0.f);
    if (row < NN) v = ((const float4*)(x + (size_t)row * D))[k4];
    uint2 pk;
    pk.x = (unsigned int)f2b(v.x) | ((unsigned int)f2b(v.y) << 16);
    pk.y = (unsigned int)f2b(v.z) | ((unsigned int)f2b(v.w) << 16);
    *((uint2*)&As[m][k4 * 4]) = pk;
  }
  __syncthreads();
  const int wv = tid >> 6;
  const int lane = tid & 63;
  const int n0 = lane & 15, q = lane >> 4;
  const int boff = q * 16 + n0;
  const bf16x8* Bp = (const bf16x8*)Bpack;

  bf16x8 a4[4];
  #pragma unroll
  for (int s = 0; s < 4; ++s)
    a4[s] = *(const bf16x8*)&As[wv * 16 + n0][s * 32 + q * 8];

  f32x4 acc[9];
  #pragma unroll
  for (int nt = 0; nt < 9; ++nt) acc[nt] = (f32x4){0.f, 0.f, 0.f, 0.f};

  #pragma unroll
  for (int s = 0; s < 4; ++s) {
    #pragma unroll
    for (int nt = 0; nt < 9; ++nt) {
      bf16x8 b = Bp[(nt * 4 + s) * 64 + boff];
      acc[nt] = __builtin_amdgcn_mfma_f32_16x16x32_bf16(a4[s], b, acc[nt], 0, 0, 0);
    }
  }
  __syncthreads();   // all waves hoisted a4; As now dead -> reuse as out-tile
  #pragma unroll
  for (int nt = 0; nt < 8; ++nt) {
    int col = nt * 16 + n0;
    float bv = b_lin[col];
    #pragma unroll
    for (int r = 0; r < 4; ++r)
      As[wv * 16 + q * 4 + r][col] = f2b(acc[nt][r] + bv);
  }
  // score cols: n0 even -> s_src4[row*4 + n0/2], odd -> s_dst4[row*4 + n0/2]
  if (n0 < 6) {
    float sb = sbuf[n0];
    float* Sout = (n0 & 1) ? s_dst4 : s_src4;
    #pragma unroll
    for (int r = 0; r < 4; ++r) {
      int row = row0 + wv * 16 + q * 4 + r;
      if (row < NN) Sout[row * 4 + (n0 >> 1)] = acc[8][r] + sb;
    }
  }
  __syncthreads();
  // coalesced write-out: 64 rows x 128 bf16 = 1024 uint4
  #pragma unroll
  for (int i = 0; i < 4; ++i) {
    int idx = tid + i * 256;          // 0..1023
    int row = idx >> 4, c16 = idx & 15;
    int grow = row0 + row;
    if (grow < NN)
      *((uint4*)&xb[(size_t)grow * D + c16 * 8]) = *((const uint4*)&As[row][c16 * 8]);
  }
}

// ---------------------------------------------------------------------------
// gather12n: r6 structure with two VALU fixes in the hot loop:
//  (1) native exp2 (__ocml_native_exp2_f32 -> single v_exp_f32). r6's plain
//      exp2f() hit the OCML correct-rounding path and REGRESSED vs r4's
//      __expf (47->50us, VALUBusy 74->84%). Native exp2 beats both.
//  (2) leaky relu as fmaxf(v, 0.2v) — 2 instrs (mul+max) vs cmp+cndmask.
// ---------------------------------------------------------------------------
__global__ __launch_bounds__(64) void gather12n(const int* __restrict__ counts,
                                                const unsigned int* __restrict__ slots8,
                                                const float4* __restrict__ s_src4,
                                                const float4* __restrict__ s_dst4,
                                                const unsigned short* __restrict__ xb,
                                                unsigned short* __restrict__ accb) {
  const int dst = blockIdx.x;
  const int lane = threadIdx.x;          // 0..63
  const int hf = lane >> 5;
  const int c = (lane & 31) * 4;         // channel base (4 channels per lane)
  int cnt = counts[dst];
  cnt = cnt < CAP ? cnt : CAP;
  const int beg = dst * CAP;
  const int end = beg + cnt;
  float4 sd = s_dst4[dst];
  float a0[4] = {0.f, 0.f, 0.f, 0.f};
  float a1[4] = {0.f, 0.f, 0.f, 0.f};
  float a2[4] = {0.f, 0.f, 0.f, 0.f};
  float d0 = 0.f, d1 = 0.f, d2 = 0.f;
  int s = beg + hf;
  for (; s + 2 < end; s += 4) {
    unsigned int seA = slots8[s];
    unsigned int seB = slots8[s + 2];
    int srcA = seA & 0xffffu, srcB = seB & 0xffffu;
    float ewA = bhi(seA), ewB = bhi(seB);
    float4 ssA = s_src4[srcA];
    float4 ssB = s_src4[srcB];
    uint2 ua = *(const uint2*)&xb[(size_t)srcA * D + c];
    uint2 ub = *(const uint2*)&xb[(size_t)srcB * D + c];
    float vA0 = ssA.x + sd.x, vA1 = ssA.y + sd.y, vA2 = ssA.z + sd.z;
    float vB0 = ssB.x + sd.x, vB1 = ssB.y + sd.y, vB2 = ssB.z + sd.z;
    // leaky(v) == max(v, 0.2v): v>0 -> v dominates; v<0 -> 0.2v dominates
    vA0 = fmaxf(vA0, 0.2f * vA0);
    vA1 = fmaxf(vA1, 0.2f * vA1);
    vA2 = fmaxf(vA2, 0.2f * vA2);
    vB0 = fmaxf(vB0, 0.2f * vB0);
    vB1 = fmaxf(vB1, 0.2f * vB1);
    vB2 = fmaxf(vB2, 0.2f * vB2);
    // scores pre-scaled by log2(e): exp(orig) == exp2(v); alpha identical
    float pA0 = __ocml_native_exp2_f32(vA0);
    float pA1 = __ocml_native_exp2_f32(vA1);
    float pA2 = __ocml_native_exp2_f32(vA2);
    float pB0 = __ocml_native_exp2_f32(vB0);
    float pB1 = __ocml_native_exp2_f32(vB1);
    float pB2 = __ocml_native_exp2_f32(vB2);
    float wa0 = pA0 * ewA, wa1 = pA1 * ewA, wa2 = pA2 * ewA;
    float wb0 = pB0 * ewB, wb1 = pB1 * ewB, wb2 = pB2 * ewB;
    float xA[4] = {blo(ua.x), bhi(ua.x), blo(ua.y), bhi(ua.y)};
    float xB[4] = {blo(ub.x), bhi(ub.x), blo(ub.y), bhi(ub.y)};
    #pragma unroll
    for (int j = 0; j < 4; ++j) {
      a0[j] += wa0 * xA[j] + wb0 * xB[j];
      a1[j] += wa1 * xA[j] + wb1 * xB[j];
      a2[j] += wa2 * xA[j] + wb2 * xB[j];
    }
    d0 += pA0 + pB0;
    d1 += pA1 + pB1;
    d2 += pA2 + pB2;
  }
  if (s < end) {
    unsigned int seA = slots8[s];
    int srcA = seA & 0xffffu;
    float ewA = bhi(seA);
    float4 ssA = s_src4[srcA];
    uint2 ua = *(const uint2*)&xb[(size_t)srcA * D + c];
    float vA0 = ssA.x + sd.x, vA1 = ssA.y + sd.y, vA2 = ssA.z + sd.z;
    vA0 = fmaxf(vA0, 0.2f * vA0);
    vA1 = fmaxf(vA1, 0.2f * vA1);
    vA2 = fmaxf(vA2, 0.2f * vA2);
    float pA0 = __ocml_native_exp2_f32(vA0);
    float pA1 = __ocml_native_exp2_f32(vA1);
    float pA2 = __ocml_native_exp2_f32(vA2);
    float w0 = pA0 * ewA, w1 = pA1 * ewA, w2 = pA2 * ewA;
    float xA[4] = {blo(ua.x), bhi(ua.x), blo(ua.y), bhi(ua.y)};
    #pragma unroll
    for (int j = 0; j < 4; ++j) {
      a0[j] += w0 * xA[j];
      a1[j] += w1 * xA[j];
      a2[j] += w2 * xA[j];
    }
    d0 += pA0; d1 += pA1; d2 += pA2;
  }
  #pragma unroll
  for (int j = 0; j < 4; ++j) {
    a0[j] += __shfl_xor(a0[j], 32, 64);
    a1[j] += __shfl_xor(a1[j], 32, 64);
    a2[j] += __shfl_xor(a2[j], 32, 64);
  }
  d0 += __shfl_xor(d0, 32, 64);
  d1 += __shfl_xor(d1, 32, 64);
  d2 += __shfl_xor(d2, 32, 64);
  if (hf == 0) {
    float r0 = 1.f / (3.f * fmaxf(d0, 1e-16f));   // fold 1/NH here
    float r1 = 1.f / (3.f * fmaxf(d1, 1e-16f));
    float r2 = 1.f / (3.f * fmaxf(d2, 1e-16f));
    unsigned short* base = accb + (size_t)dst * (NH * D);
    uint2 o;
    o.x = (unsigned int)f2h(a0[0] * r0) | ((unsigned int)f2h(a0[1] * r0) << 16);
    o.y = (unsigned int)f2h(a0[2] * r0) | ((unsigned int)f2h(a0[3] * r0) << 16);
    *(uint2*)&base[c] = o;
    o.x = (unsigned int)f2h(a1[0] * r1) | ((unsigned int)f2h(a1[1] * r1) << 16);
    o.y = (unsigned int)f2h(a1[2] * r1) | ((unsigned int)f2h(a1[3] * r1) << 16);
    *(uint2*)&base[D + c] = o;
    o.x = (unsigned int)f2h(a2[0] * r2) | ((unsigned int)f2h(a2[1] * r2) << 16);
    o.y = (unsigned int)f2h(a2[2] * r2) | ((unsigned int)f2h(a2[3] * r2) << 16);
    *(uint2*)&base[2 * D + c] = o;
  }
}

// ---------------------------------------------------------------------------
// final_gemm16: unchanged r6 (control). Single-pass f16 MFMA.
// ---------------------------------------------------------------------------
__global__ __launch_bounds__(256) void final_gemm16(const unsigned short* __restrict__ accb,
                                                    const uint4* __restrict__ Wpack3,
                                                    const float* __restrict__ bcomb2,
                                                    float* __restrict__ out) {
  const int row0 = blockIdx.x * 64;
  const int tid = threadIdx.x;
  __shared__ __align__(16) _Float16 Af[64][136];
  const int wv = tid >> 6;
  const int lane = tid & 63;
  const int n0 = lane & 15, q = lane >> 4;
  const int boff = q * 16 + n0;

  f32x4 o[8];
  #pragma unroll
  for (int nt = 0; nt < 8; ++nt) o[nt] = (f32x4){0.f, 0.f, 0.f, 0.f};

  for (int ck = 0; ck < NH; ++ck) {
    if (ck) __syncthreads();              // prior frag reads done before restage
    #pragma unroll
    for (int it = 0; it < 4; ++it) {
      int idx = tid + it * 256;           // 0..1023
      int m = idx >> 4, k8 = idx & 15;
      int row = row0 + m;
      uint4 u = make_uint4(0, 0, 0, 0);
      if (row < NN)
        u = *(const uint4*)&accb[(size_t)row * (NH * D) + ck * D + k8 * 8];
      *((uint4*)&Af[m][k8 * 8]) = u;      // direct copy: accb is already fp16
    }
    __syncthreads();
    f16x8 af[4];
    #pragma unroll
    for (int s = 0; s < 4; ++s)
      af[s] = *(const f16x8*)&Af[wv * 16 + n0][s * 32 + q * 8];
    const f16x8* Bp = (const f16x8*)(Wpack3 + ck * 2048);
    #pragma unroll
    for (int s = 0; s < 4; ++s) {
      #pragma unroll
      for (int nt = 0; nt < 8; ++nt) {
        f16x8 b = Bp[(nt * 4 + s) * 64 + boff];
        o[nt] = __builtin_amdgcn_mfma_f32_16x16x32_f16(af[s], b, o[nt], 0, 0, 0);
      }
    }
  }
  // epilogue: 16-lane groups write 64B-contiguous fp32 segments
  #pragma unroll
  for (int nt = 0; nt < 8; ++nt) {
    int col = nt * 16 + n0;
    float bv = bcomb2[col];
    #pragma unroll
    for (int r = 0; r < 4; ++r) {
      int row = row0 + wv * 16 + q * 4 + r;
      if (row < NN) out[(size_t)row * D + col] = o[nt][r] + bv;
    }
  }
}

// ---------------------------------------------------------------------------
extern "C" void kernel_launch(void* const* d_in, const int* in_sizes, int n_in,
                              void* d_out, int out_size, void* d_ws, size_t ws_size,
                              hipStream_t stream) {
  const float* x          = (const float*)d_in[0];
  const int*   ei         = (const int*)d_in[1];
  const int*   eid        = (const int*)d_in[2];
  const float* ddi        = (const float*)d_in[3];
  const float* W_lin      = (const float*)d_in[4];
  const float* b_lin      = (const float*)d_in[5];
  const float* emb        = (const float*)d_in[6];
  const float* W_heads    = (const float*)d_in[7];
  const float* att_src    = (const float*)d_in[8];
  const float* att_dst    = (const float*)d_in[9];
  const float* bias_heads = (const float*)d_in[10];
  float* out = (float*)d_out;

  // workspace layout (16B-aligned chunks first); total ~66 MB
  uint4*  Bpack  = (uint4*)d_ws;                               // 2304 (W_lin | 6 score cols)
  uint4*  Wpack3 = Bpack + 2304;                               // 3*2048 (W_heads fp16)
  unsigned short* xb = (unsigned short*)(Wpack3 + NH * 2048);  // NN*D bf16 (12.8MB)
  unsigned int* slots8 = (unsigned int*)(xb + (size_t)NN * D); // NN*CAP (12.8MB)
  unsigned short* accb = (unsigned short*)(slots8 + (size_t)NN * CAP); // NN*384 fp16 (38.4MB)
  float*  sbuf   = (float*)(accb + (size_t)NN * NH * D);       // 8
  float*  bcomb2 = sbuf + 8;                                   // 128
  float*  s_src4 = bcomb2 + 128;                               // NN*4 (stride-4)
  float*  s_dst4 = s_src4 + (size_t)NN * 4;                    // NN*4
  int*    counts = (int*)(s_dst4 + (size_t)NN * 4);            // NN

  // 0. zero bucket counts
  hipMemsetAsync(counts, 0, (size_t)NN * sizeof(int), stream);
  // 1. scatter (t=0) + W repacks + scaled score cols + bcomb2 (control)
  pack_scatter2<<<EDGE_BLOCKS + 36, 256, 0, stream>>>(
      W_lin, W_heads, att_src, att_dst, b_lin, bias_heads, ei, eid, ddi, emb,
      Bpack, Wpack3, sbuf, bcomb2, counts, slots8);
  // 2. x_tilde + score columns (control)
  mfma_x<<<MFMA_BLOCKS, 256, 0, stream>>>(x, Bpack, b_lin, sbuf, xb,
                                          s_src4, s_dst4);
  // 3. per-dst gather: native exp2 + fmax-leaky (VALU slimming)
  gather12n<<<NN, 64, 0, stream>>>(counts, slots8, (const float4*)s_src4,
                                   (const float4*)s_dst4, xb, accb);
  // 4. dense epilogue (control)
  final_gemm16<<<MFMA_BLOCKS, 256, 0, stream>>>(accb, Wpack3, bcomb2, out);
}

// Round 10
// 207.340 us; speedup vs baseline: 1.2017x; 1.0262x over previous
//
#include <hip/hip_runtime.h>
#include <math.h>

#define NN 50000
#define NE 600000
#define D 128
#define NH 3
#define CAP 64                              // max degree bucket (lambda=12, P(>=64)~1e-30)
#define CSTRIDE 16                          // counts padded: 1 dst per 64B line
#define EDGE_BLOCKS ((NE + 255) / 256)      // 2344
#define MFMA_BLOCKS ((NN + 63) / 64)        // 782
#define LOG2E 1.44269504088896340736f

typedef short bf16x8 __attribute__((ext_vector_type(8)));
typedef _Float16 f16x8 __attribute__((ext_vector_type(8)));
typedef float f32x4 __attribute__((ext_vector_type(4)));

extern "C" __device__ float __ocml_native_exp2_f32(float);   // single v_exp_f32

__device__ __forceinline__ unsigned short f2b(float f) {
  unsigned int u = __float_as_uint(f);
  u += 0x7FFF + ((u >> 16) & 1);            // round-to-nearest-even
  return (unsigned short)(u >> 16);
}
__device__ __forceinline__ float blo(unsigned int u) {
  return __uint_as_float(u << 16);
}
__device__ __forceinline__ float bhi(unsigned int u) {
  return __uint_as_float(u & 0xffff0000u);
}
__device__ __forceinline__ unsigned short f2h(float f) {
  _Float16 t = (_Float16)f;
  return *(unsigned short*)&t;
}

// ---------------------------------------------------------------------------
// pack_scatter2: r9 structure; ONE change: counts is line-padded (stride 16).
// r9 PMC (VALUBusy 0.57%, occ 44%, 50us) = coherence-stall signature. 16
// dsts/64B line x 8 non-coherent XCDs -> ~170 line-ownership transfers per
// line at the atomic coherence point ~= the full 50us. Padding cuts
// same-line contention 192 -> 12 (true same-dst only).
// ---------------------------------------------------------------------------
__global__ __launch_bounds__(256) void pack_scatter2(const float* __restrict__ W_lin,
                                                     const float* __restrict__ W_heads,
                                                     const float* __restrict__ att_src,
                                                     const float* __restrict__ att_dst,
                                                     const float* __restrict__ b_lin,
                                                     const float* __restrict__ bias_heads,
                                                     const int* __restrict__ ei,
                                                     const int* __restrict__ eid,
                                                     const float* __restrict__ ddi,
                                                     const float* __restrict__ emb,
                                                     uint4* __restrict__ Bpack,
                                                     uint4* __restrict__ Wpack3,
                                                     float* __restrict__ sbuf,
                                                     float* __restrict__ bcomb2,
                                                     int* __restrict__ counts,
                                                     unsigned int* __restrict__ slots8) {
  const int bx = blockIdx.x;
  const int tid = threadIdx.x;
  if (bx < EDGE_BLOCKS) {
    int e = bx * 256 + tid;
    if (e < NE) {
      int src = ei[e], dst = ei[NE + e];
      int idx = atomicAdd(&counts[dst * CSTRIDE], 1);
      idx = idx < CAP ? idx : CAP - 1;   // safety clamp (statistically unreachable)
      float ew = emb[eid[e]] - ddi[e];
      slots8[dst * CAP + idx] = (unsigned int)src | ((unsigned int)f2b(ew) << 16);
    }
    return;
  }
  const int pb = bx - EDGE_BLOCKS;
  if (pb < 8) {
    int r = pb * 256 + tid;              // 0..2047
    int nt = r >> 8, s = (r >> 6) & 3, q = (r >> 4) & 3, n0 = r & 15;
    int kbase = s * 32 + q * 8;
    int n = nt * 16 + n0;
    unsigned int w[4];
    #pragma unroll
    for (int p = 0; p < 4; ++p) {
      unsigned short lo = f2b(W_lin[(kbase + 2 * p) * D + n]);
      unsigned short hi = f2b(W_lin[(kbase + 2 * p + 1) * D + n]);
      w[p] = (unsigned int)lo | ((unsigned int)hi << 16);
    }
    Bpack[r] = make_uint4(w[0], w[1], w[2], w[3]);
  } else if (pb < 32) {
    int u = (pb - 8) * 256 + tid;        // 0..6143
    int h = u >> 11, r = u & 2047;
    int nt = r >> 8, s = (r >> 6) & 3, q = (r >> 4) & 3, n0 = r & 15;
    int kbase = s * 32 + q * 8;
    int n = nt * 16 + n0;
    const float* W = W_heads + (size_t)h * D * D;
    unsigned int w[4];
    #pragma unroll
    for (int p = 0; p < 4; ++p) {
      unsigned short lo = f2h(W[(kbase + 2 * p) * D + n]);
      unsigned short hi = f2h(W[(kbase + 2 * p + 1) * D + n]);
      w[p] = (unsigned int)lo | ((unsigned int)hi << 16);
    }
    Wpack3[h * 2048 + r] = make_uint4(w[0], w[1], w[2], w[3]);
  } else if (pb < 35) {
    const int h = pb - 32;
    __shared__ float wha_s[128], wha_d[128], scs[128], scd[128];
    {
      int m = tid & 127;
      const float* W = W_heads + (size_t)h * D * D + m * D;
      const float* a = (tid < 128) ? (att_src + h * D) : (att_dst + h * D);
      float acc = 0.f;
      for (int n = 0; n < D; ++n) acc += W[n] * a[n];
      if (tid < 128) wha_s[m] = acc; else wha_d[m] = acc;
    }
    __syncthreads();
    {
      int k = tid & 127;
      const float* wl = W_lin + k * D;
      const float* wha = (tid < 128) ? wha_s : wha_d;
      float acc = 0.f;
      for (int m = 0; m < D; ++m) acc += wl[m] * wha[m];
      if (tid < 128) scs[k] = acc * LOG2E; else scd[k] = acc * LOG2E;
    }
    __syncthreads();
    if (tid < 2) {
      const float* wha = tid ? wha_d : wha_s;
      float a = 0.f;
      for (int k = 0; k < D; ++k) a += b_lin[k] * wha[k];
      sbuf[h * 2 + tid] = a * LOG2E;     // sbuf = [s0,d0,s1,d1,s2,d2] (scaled)
    }
    {
      int s = (tid >> 6) & 3, q = (tid >> 4) & 3, n0 = tid & 15;
      int kbase = s * 32 + q * 8;
      bool mine = (n0 < 6) && ((n0 >> 1) == h);
      bool zero = (h == 0) && (n0 >= 6);
      if (mine || zero) {
        float vals[8];
        #pragma unroll
        for (int j = 0; j < 8; ++j)
          vals[j] = zero ? 0.f : ((n0 & 1) ? scd[kbase + j] : scs[kbase + j]);
        unsigned int w[4];
        #pragma unroll
        for (int p = 0; p < 4; ++p)
          w[p] = (unsigned int)f2b(vals[2 * p]) | ((unsigned int)f2b(vals[2 * p + 1]) << 16);
        Bpack[2048 + tid] = make_uint4(w[0], w[1], w[2], w[3]);
      }
    }
  } else {
    if (tid < D)
      bcomb2[tid] = (bias_heads[tid] + bias_heads[D + tid] + bias_heads[2 * D + tid]) * (1.f / 3.f);
  }
}

// ---------------------------------------------------------------------------
// mfma_x: unchanged r6/r9 (control).
// ---------------------------------------------------------------------------
__global__ __launch_bounds__(256) void mfma_x(const float* __restrict__ x,
                                              const uint4* __restrict__ Bpack,
                                              const float* __restrict__ b_lin,
                                              const float* __restrict__ sbuf,
                                              unsigned short* __restrict__ xb,
                                              float* __restrict__ s_src4,
                                              float* __restrict__ s_dst4) {
  const int row0 = blockIdx.x * 64;
  const int tid = threadIdx.x;
  __shared__ __align__(16) unsigned short As[64][136];
  #pragma unroll
  for (int it = 0; it < 8; ++it) {
    int idx = tid + it * 256;
    int m = idx >> 5, k4 = idx & 31;
    int row = row0 + m;
    float4 v = make_float4(0.f, 0.f, 0.f, 0.f);
    if (row < NN) v = ((const float4*)(x + (size_t)row * D))[k4];
    uint2 pk;
    pk.x = (unsigned int)f2b(v.x) | ((unsigned int)f2b(v.y) << 16);
    pk.y = (unsigned int)f2b(v.z) | ((unsigned int)f2b(v.w) << 16);
    *((uint2*)&As[m][k4 * 4]) = pk;
  }
  __syncthreads();
  const int wv = tid >> 6;
  const int lane = tid & 63;
  const int n0 = lane & 15, q = lane >> 4;
  const int boff = q * 16 + n0;
  const bf16x8* Bp = (const bf16x8*)Bpack;

  bf16x8 a4[4];
  #pragma unroll
  for (int s = 0; s < 4; ++s)
    a4[s] = *(const bf16x8*)&As[wv * 16 + n0][s * 32 + q * 8];

  f32x4 acc[9];
  #pragma unroll
  for (int nt = 0; nt < 9; ++nt) acc[nt] = (f32x4){0.f, 0.f, 0.f, 0.f};

  #pragma unroll
  for (int s = 0; s < 4; ++s) {
    #pragma unroll
    for (int nt = 0; nt < 9; ++nt) {
      bf16x8 b = Bp[(nt * 4 + s) * 64 + boff];
      acc[nt] = __builtin_amdgcn_mfma_f32_16x16x32_bf16(a4[s], b, acc[nt], 0, 0, 0);
    }
  }
  __syncthreads();   // all waves hoisted a4; As now dead -> reuse as out-tile
  #pragma unroll
  for (int nt = 0; nt < 8; ++nt) {
    int col = nt * 16 + n0;
    float bv = b_lin[col];
    #pragma unroll
    for (int r = 0; r < 4; ++r)
      As[wv * 16 + q * 4 + r][col] = f2b(acc[nt][r] + bv);
  }
  // score cols: n0 even -> s_src4[row*4 + n0/2], odd -> s_dst4[row*4 + n0/2]
  if (n0 < 6) {
    float sb = sbuf[n0];
    float* Sout = (n0 & 1) ? s_dst4 : s_src4;
    #pragma unroll
    for (int r = 0; r < 4; ++r) {
      int row = row0 + wv * 16 + q * 4 + r;
      if (row < NN) Sout[row * 4 + (n0 >> 1)] = acc[8][r] + sb;
    }
  }
  __syncthreads();
  // coalesced write-out: 64 rows x 128 bf16 = 1024 uint4
  #pragma unroll
  for (int i = 0; i < 4; ++i) {
    int idx = tid + i * 256;          // 0..1023
    int row = idx >> 4, c16 = idx & 15;
    int grow = row0 + row;
    if (grow < NN)
      *((uint4*)&xb[(size_t)grow * D + c16 * 8]) = *((const uint4*)&As[row][c16 * 8]);
  }
}

// ---------------------------------------------------------------------------
// gather12n: unchanged r9 (control) except the padded counts read.
// ---------------------------------------------------------------------------
__global__ __launch_bounds__(64) void gather12n(const int* __restrict__ counts,
                                                const unsigned int* __restrict__ slots8,
                                                const float4* __restrict__ s_src4,
                                                const float4* __restrict__ s_dst4,
                                                const unsigned short* __restrict__ xb,
                                                unsigned short* __restrict__ accb) {
  const int dst = blockIdx.x;
  const int lane = threadIdx.x;          // 0..63
  const int hf = lane >> 5;
  const int c = (lane & 31) * 4;         // channel base (4 channels per lane)
  int cnt = counts[dst * CSTRIDE];
  cnt = cnt < CAP ? cnt : CAP;
  const int beg = dst * CAP;
  const int end = beg + cnt;
  float4 sd = s_dst4[dst];
  float a0[4] = {0.f, 0.f, 0.f, 0.f};
  float a1[4] = {0.f, 0.f, 0.f, 0.f};
  float a2[4] = {0.f, 0.f, 0.f, 0.f};
  float d0 = 0.f, d1 = 0.f, d2 = 0.f;
  int s = beg + hf;
  for (; s + 2 < end; s += 4) {
    unsigned int seA = slots8[s];
    unsigned int seB = slots8[s + 2];
    int srcA = seA & 0xffffu, srcB = seB & 0xffffu;
    float ewA = bhi(seA), ewB = bhi(seB);
    float4 ssA = s_src4[srcA];
    float4 ssB = s_src4[srcB];
    uint2 ua = *(const uint2*)&xb[(size_t)srcA * D + c];
    uint2 ub = *(const uint2*)&xb[(size_t)srcB * D + c];
    float vA0 = ssA.x + sd.x, vA1 = ssA.y + sd.y, vA2 = ssA.z + sd.z;
    float vB0 = ssB.x + sd.x, vB1 = ssB.y + sd.y, vB2 = ssB.z + sd.z;
    // leaky(v) == max(v, 0.2v)
    vA0 = fmaxf(vA0, 0.2f * vA0);
    vA1 = fmaxf(vA1, 0.2f * vA1);
    vA2 = fmaxf(vA2, 0.2f * vA2);
    vB0 = fmaxf(vB0, 0.2f * vB0);
    vB1 = fmaxf(vB1, 0.2f * vB1);
    vB2 = fmaxf(vB2, 0.2f * vB2);
    // scores pre-scaled by log2(e): exp(orig) == exp2(v); alpha identical
    float pA0 = __ocml_native_exp2_f32(vA0);
    float pA1 = __ocml_native_exp2_f32(vA1);
    float pA2 = __ocml_native_exp2_f32(vA2);
    float pB0 = __ocml_native_exp2_f32(vB0);
    float pB1 = __ocml_native_exp2_f32(vB1);
    float pB2 = __ocml_native_exp2_f32(vB2);
    float wa0 = pA0 * ewA, wa1 = pA1 * ewA, wa2 = pA2 * ewA;
    float wb0 = pB0 * ewB, wb1 = pB1 * ewB, wb2 = pB2 * ewB;
    float xA[4] = {blo(ua.x), bhi(ua.x), blo(ua.y), bhi(ua.y)};
    float xB[4] = {blo(ub.x), bhi(ub.x), blo(ub.y), bhi(ub.y)};
    #pragma unroll
    for (int j = 0; j < 4; ++j) {
      a0[j] += wa0 * xA[j] + wb0 * xB[j];
      a1[j] += wa1 * xA[j] + wb1 * xB[j];
      a2[j] += wa2 * xA[j] + wb2 * xB[j];
    }
    d0 += pA0 + pB0;
    d1 += pA1 + pB1;
    d2 += pA2 + pB2;
  }
  if (s < end) {
    unsigned int seA = slots8[s];
    int srcA = seA & 0xffffu;
    float ewA = bhi(seA);
    float4 ssA = s_src4[srcA];
    uint2 ua = *(const uint2*)&xb[(size_t)srcA * D + c];
    float vA0 = ssA.x + sd.x, vA1 = ssA.y + sd.y, vA2 = ssA.z + sd.z;
    vA0 = fmaxf(vA0, 0.2f * vA0);
    vA1 = fmaxf(vA1, 0.2f * vA1);
    vA2 = fmaxf(vA2, 0.2f * vA2);
    float pA0 = __ocml_native_exp2_f32(vA0);
    float pA1 = __ocml_native_exp2_f32(vA1);
    float pA2 = __ocml_native_exp2_f32(vA2);
    float w0 = pA0 * ewA, w1 = pA1 * ewA, w2 = pA2 * ewA;
    float xA[4] = {blo(ua.x), bhi(ua.x), blo(ua.y), bhi(ua.y)};
    #pragma unroll
    for (int j = 0; j < 4; ++j) {
      a0[j] += w0 * xA[j];
      a1[j] += w1 * xA[j];
      a2[j] += w2 * xA[j];
    }
    d0 += pA0; d1 += pA1; d2 += pA2;
  }
  #pragma unroll
  for (int j = 0; j < 4; ++j) {
    a0[j] += __shfl_xor(a0[j], 32, 64);
    a1[j] += __shfl_xor(a1[j], 32, 64);
    a2[j] += __shfl_xor(a2[j], 32, 64);
  }
  d0 += __shfl_xor(d0, 32, 64);
  d1 += __shfl_xor(d1, 32, 64);
  d2 += __shfl_xor(d2, 32, 64);
  if (hf == 0) {
    float r0 = 1.f / (3.f * fmaxf(d0, 1e-16f));   // fold 1/NH here
    float r1 = 1.f / (3.f * fmaxf(d1, 1e-16f));
    float r2 = 1.f / (3.f * fmaxf(d2, 1e-16f));
    unsigned short* base = accb + (size_t)dst * (NH * D);
    uint2 o;
    o.x = (unsigned int)f2h(a0[0] * r0) | ((unsigned int)f2h(a0[1] * r0) << 16);
    o.y = (unsigned int)f2h(a0[2] * r0) | ((unsigned int)f2h(a0[3] * r0) << 16);
    *(uint2*)&base[c] = o;
    o.x = (unsigned int)f2h(a1[0] * r1) | ((unsigned int)f2h(a1[1] * r1) << 16);
    o.y = (unsigned int)f2h(a1[2] * r1) | ((unsigned int)f2h(a1[3] * r1) << 16);
    *(uint2*)&base[D + c] = o;
    o.x = (unsigned int)f2h(a2[0] * r2) | ((unsigned int)f2h(a2[1] * r2) << 16);
    o.y = (unsigned int)f2h(a2[2] * r2) | ((unsigned int)f2h(a2[3] * r2) << 16);
    *(uint2*)&base[2 * D + c] = o;
  }
}

// ---------------------------------------------------------------------------
// final_gemm16: unchanged r6/r9 (control). Single-pass f16 MFMA.
// ---------------------------------------------------------------------------
__global__ __launch_bounds__(256) void final_gemm16(const unsigned short* __restrict__ accb,
                                                    const uint4* __restrict__ Wpack3,
                                                    const float* __restrict__ bcomb2,
                                                    float* __restrict__ out) {
  const int row0 = blockIdx.x * 64;
  const int tid = threadIdx.x;
  __shared__ __align__(16) _Float16 Af[64][136];
  const int wv = tid >> 6;
  const int lane = tid & 63;
  const int n0 = lane & 15, q = lane >> 4;
  const int boff = q * 16 + n0;

  f32x4 o[8];
  #pragma unroll
  for (int nt = 0; nt < 8; ++nt) o[nt] = (f32x4){0.f, 0.f, 0.f, 0.f};

  for (int ck = 0; ck < NH; ++ck) {
    if (ck) __syncthreads();              // prior frag reads done before restage
    #pragma unroll
    for (int it = 0; it < 4; ++it) {
      int idx = tid + it * 256;           // 0..1023
      int m = idx >> 4, k8 = idx & 15;
      int row = row0 + m;
      uint4 u = make_uint4(0, 0, 0, 0);
      if (row < NN)
        u = *(const uint4*)&accb[(size_t)row * (NH * D) + ck * D + k8 * 8];
      *((uint4*)&Af[m][k8 * 8]) = u;      // direct copy: accb is already fp16
    }
    __syncthreads();
    f16x8 af[4];
    #pragma unroll
    for (int s = 0; s < 4; ++s)
      af[s] = *(const f16x8*)&Af[wv * 16 + n0][s * 32 + q * 8];
    const f16x8* Bp = (const f16x8*)(Wpack3 + ck * 2048);
    #pragma unroll
    for (int s = 0; s < 4; ++s) {
      #pragma unroll
      for (int nt = 0; nt < 8; ++nt) {
        f16x8 b = Bp[(nt * 4 + s) * 64 + boff];
        o[nt] = __builtin_amdgcn_mfma_f32_16x16x32_f16(af[s], b, o[nt], 0, 0, 0);
      }
    }
  }
  // epilogue: 16-lane groups write 64B-contiguous fp32 segments
  #pragma unroll
  for (int nt = 0; nt < 8; ++nt) {
    int col = nt * 16 + n0;
    float bv = bcomb2[col];
    #pragma unroll
    for (int r = 0; r < 4; ++r) {
      int row = row0 + wv * 16 + q * 4 + r;
      if (row < NN) out[(size_t)row * D + col] = o[nt][r] + bv;
    }
  }
}

// ---------------------------------------------------------------------------
extern "C" void kernel_launch(void* const* d_in, const int* in_sizes, int n_in,
                              void* d_out, int out_size, void* d_ws, size_t ws_size,
                              hipStream_t stream) {
  const float* x          = (const float*)d_in[0];
  const int*   ei         = (const int*)d_in[1];
  const int*   eid        = (const int*)d_in[2];
  const float* ddi        = (const float*)d_in[3];
  const float* W_lin      = (const float*)d_in[4];
  const float* b_lin      = (const float*)d_in[5];
  const float* emb        = (const float*)d_in[6];
  const float* W_heads    = (const float*)d_in[7];
  const float* att_src    = (const float*)d_in[8];
  const float* att_dst    = (const float*)d_in[9];
  const float* bias_heads = (const float*)d_in[10];
  float* out = (float*)d_out;

  // workspace layout (16B-aligned chunks first); total ~69 MB
  uint4*  Bpack  = (uint4*)d_ws;                               // 2304 (W_lin | 6 score cols)
  uint4*  Wpack3 = Bpack + 2304;                               // 3*2048 (W_heads fp16)
  unsigned short* xb = (unsigned short*)(Wpack3 + NH * 2048);  // NN*D bf16 (12.8MB)
  unsigned int* slots8 = (unsigned int*)(xb + (size_t)NN * D); // NN*CAP (12.8MB)
  unsigned short* accb = (unsigned short*)(slots8 + (size_t)NN * CAP); // NN*384 fp16 (38.4MB)
  float*  sbuf   = (float*)(accb + (size_t)NN * NH * D);       // 8
  float*  bcomb2 = sbuf + 8;                                   // 128
  float*  s_src4 = bcomb2 + 128;                               // NN*4 (stride-4)
  float*  s_dst4 = s_src4 + (size_t)NN * 4;                    // NN*4
  int*    counts = (int*)(s_dst4 + (size_t)NN * 4);            // NN*CSTRIDE (3.2MB, line-padded)

  // 0. zero padded bucket counts (3.2MB)
  hipMemsetAsync(counts, 0, (size_t)NN * CSTRIDE * sizeof(int), stream);
  // 1. scatter (t=0, line-padded atomics) + W repacks + score cols + bcomb2
  pack_scatter2<<<EDGE_BLOCKS + 36, 256, 0, stream>>>(
      W_lin, W_heads, att_src, att_dst, b_lin, bias_heads, ei, eid, ddi, emb,
      Bpack, Wpack3, sbuf, bcomb2, counts, slots8);
  // 2. x_tilde + score columns (control)
  mfma_x<<<MFMA_BLOCKS, 256, 0, stream>>>(x, Bpack, b_lin, sbuf, xb,
                                          s_src4, s_dst4);
  // 3. per-dst gather (control, padded counts read)
  gather12n<<<NN, 64, 0, stream>>>(counts, slots8, (const float4*)s_src4,
                                   (const float4*)s_dst4, xb, accb);
  // 4. dense epilogue (control)
  final_gemm16<<<MFMA_BLOCKS, 256, 0, stream>>>(accb, Wpack3, bcomb2, out);
}